// Round 7
// baseline (547.669 us; speedup 1.0000x reference)
//
#include <hip/hip_runtime.h>
#include <math.h>

#define SEQ    577
#define BATCH  32
#define DIM    768
#define NHEAD  12
#define HDIM   64
#define MROWS  (BATCH * SEQ)      // 18464
#define QKVN   (3 * DIM)          // 2304

using half4   = __attribute__((ext_vector_type(4))) _Float16;
using half8   = __attribute__((ext_vector_type(8))) _Float16;
using floatx4 = __attribute__((ext_vector_type(4))) float;

typedef __attribute__((address_space(1))) const unsigned int GU;
typedef __attribute__((address_space(3))) unsigned int LU;

__device__ __forceinline__ void gld_lds16(const _Float16* g, _Float16* l) {
    __builtin_amdgcn_global_load_lds((const GU*)g, (LU*)l, 16, 0, 0);
}

__device__ __forceinline__ unsigned lds_addr(const void* p) {
    return (unsigned)(size_t)(LU*)p;   // addrspacecast generic -> LDS offset
}

// ---------------------------------------------------------------------------
// fp32 -> fp16 convert, 3 segments in one launch (x, Wqkv, Wproj).
// ---------------------------------------------------------------------------
__global__ void cvt3_f32_f16(const float* __restrict__ a, _Float16* __restrict__ ao, int na4,
                             const float* __restrict__ b, _Float16* __restrict__ bo, int nb4,
                             const float* __restrict__ c, _Float16* __restrict__ co, int nc4)
{
    int i = blockIdx.x * blockDim.x + threadIdx.x;
    int stride = gridDim.x * blockDim.x;
    int total = na4 + nb4 + nc4;
    for (; i < total; i += stride) {
        const float4* src; half4* dst; int j = i;
        if (j < na4)            { src = (const float4*)a; dst = (half4*)ao; }
        else if ((j -= na4) < nb4) { src = (const float4*)b; dst = (half4*)bo; }
        else { j -= nb4;          src = (const float4*)c; dst = (half4*)co; }
        float4 v = src[j];
        half4 h;
        h[0] = (_Float16)v.x; h[1] = (_Float16)v.y;
        h[2] = (_Float16)v.z; h[3] = (_Float16)v.w;
        dst[j] = h;
    }
}

// ---------------------------------------------------------------------------
// fp16 GEMM v5: C[M,N]=A[M,K]@B[N,K]^T (+bias). 128x128 tile, 2x2 waves,
// 4x4 frags of v_mfma_f32_16x16x32_f16, GROUP_M=8 L2 swizzle.
//
// v5: NO LDS, NO BARRIERS. Post-mortem R4-R6: three schedule variants
// (1-deep dbuf, counted-vmcnt 2-deep, 2x occupancy) all landed at 105us /
// MfmaUtil 26%. The invariant was LDS traffic: per block-K-step the LDS
// pipe serves ~512 cy (32 ds_read_b128 + 16KB gld_lds writes) vs ~310 cy
// of matrix work -> LDS-pipe-bound at exactly the measured 26%. In this
// block shape each staged byte is read by only TWO waves, so LDS buys 2x
// traffic reduction into a non-binding resource (HBM at 10-18%) while
// consuming the binding one.
// Fix: the 16x16x32 A/B fragment is 16B contiguous per lane in row-major
// memory (A[row][k+quad*8]) -> load global->reg directly with one
// global_load_dwordx4 per frag. Intra-block 2x reuse served by L1 (per-step
// working set 16KB < 32KB L1); B panels are L2-resident. Register
// double-buffer (static indices via macro, rule #20): prefetch step t+1's
// 8 frags during step t's 16 MFMAs (~900cy cover vs ~225cy L2 latency).
// Loop body = 8 global_load_dwordx4 + 16 MFMA + ~16 VALU. No __shared__,
// no s_barrier, waves fully independent.
//
// SCALEQ: multiply cols < DIM by scale*log2(e) in the f32 epilogue so the
// attention kernel can exp2 the raw MFMA scores with no per-element mul.
// ---------------------------------------------------------------------------
template<int OUT_HALF, int HAS_BIAS, int SCALEQ>
__global__ __launch_bounds__(256) void gemm_f16_reg(
    const _Float16* __restrict__ A, const _Float16* __restrict__ B,
    const float* __restrict__ bias, void* __restrict__ Cp,
    int M, int N, int K, int npm, int npn)
{
    const int GROUP = 8;
    int pid  = blockIdx.x;
    int ngrp = GROUP * npn;
    int g    = pid / ngrp;
    int fm   = g * GROUP;
    int gm   = npm - fm; if (gm > GROUP) gm = GROUP;
    int pm   = fm + (pid % ngrp) % gm;
    int pn   = (pid % ngrp) / gm;
    const int m0 = pm * 128, n0 = pn * 128;

    const int t    = threadIdx.x, lane = t & 63, wv = t >> 6;
    const int quad = lane >> 4,   ln   = lane & 15;
    const int wm   = wv >> 1,     wn   = wv & 1;

    floatx4 acc[4][4];
#pragma unroll
    for (int mt = 0; mt < 4; mt++)
#pragma unroll
        for (int nt = 0; nt < 4; nt++) acc[mt][nt] = {0.f, 0.f, 0.f, 0.f};

    // ---- per-lane fragment base pointers (frag = 16B at [row][k+quad*8]) ----
    int r0 = m0 + wm * 64 +  0 + ln; if (r0 > M - 1) r0 = M - 1;
    int r1 = m0 + wm * 64 + 16 + ln; if (r1 > M - 1) r1 = M - 1;
    int r2 = m0 + wm * 64 + 32 + ln; if (r2 > M - 1) r2 = M - 1;
    int r3 = m0 + wm * 64 + 48 + ln; if (r3 > M - 1) r3 = M - 1;
    const _Float16* Ap0 = A + (size_t)r0 * K + quad * 8;
    const _Float16* Ap1 = A + (size_t)r1 * K + quad * 8;
    const _Float16* Ap2 = A + (size_t)r2 * K + quad * 8;
    const _Float16* Ap3 = A + (size_t)r3 * K + quad * 8;
    const int c0 = n0 + wn * 64;                 // N is a multiple of 128: no clamp
    const _Float16* Bp0 = B + (size_t)(c0 +  0 + ln) * K + quad * 8;
    const _Float16* Bp1 = B + (size_t)(c0 + 16 + ln) * K + quad * 8;
    const _Float16* Bp2 = B + (size_t)(c0 + 32 + ln) * K + quad * 8;
    const _Float16* Bp3 = B + (size_t)(c0 + 48 + ln) * K + quad * 8;

    const int nk = K >> 5;                       // 24 K-steps of 32

    half8 fa[2][4], fb[2][4];                    // reg double-buffer (static idx)

    // ---- prologue: load step 0 into buffer 0 ----
    fa[0][0] = *(const half8*)(Ap0); fa[0][1] = *(const half8*)(Ap1);
    fa[0][2] = *(const half8*)(Ap2); fa[0][3] = *(const half8*)(Ap3);
    fb[0][0] = *(const half8*)(Bp0); fb[0][1] = *(const half8*)(Bp1);
    fb[0][2] = *(const half8*)(Bp2); fb[0][3] = *(const half8*)(Bp3);

    // compute on buffer C while prefetching step TT+1 into buffer N.
    // (last step's clamp re-loads current k; harmless, stays in bounds)
#define GSTEP(C, Nb, TT)                                                    \
    {                                                                       \
        const int khn = (((TT) + 1 < nk) ? (TT) + 1 : (TT)) << 5;           \
        fa[Nb][0] = *(const half8*)(Ap0 + khn);                             \
        fa[Nb][1] = *(const half8*)(Ap1 + khn);                             \
        fa[Nb][2] = *(const half8*)(Ap2 + khn);                             \
        fa[Nb][3] = *(const half8*)(Ap3 + khn);                             \
        fb[Nb][0] = *(const half8*)(Bp0 + khn);                             \
        fb[Nb][1] = *(const half8*)(Bp1 + khn);                             \
        fb[Nb][2] = *(const half8*)(Bp2 + khn);                             \
        fb[Nb][3] = *(const half8*)(Bp3 + khn);                             \
        _Pragma("unroll")                                                   \
        for (int mt = 0; mt < 4; mt++)                                      \
            _Pragma("unroll")                                               \
            for (int nt = 0; nt < 4; nt++)                                  \
                acc[mt][nt] = __builtin_amdgcn_mfma_f32_16x16x32_f16(       \
                    fa[C][mt], fb[C][nt], acc[mt][nt], 0, 0, 0);            \
    }

    for (int it = 0; it < nk; it += 2) {         // nk = 24 (even)
        GSTEP(0, 1, it);
        GSTEP(1, 0, it + 1);
    }
#undef GSTEP

    float bv[4];
    if constexpr (HAS_BIAS) {
#pragma unroll
        for (int nt = 0; nt < 4; nt++) bv[nt] = bias[n0 + wn * 64 + nt * 16 + ln];
    }
    float*    C32 = (float*)Cp;
    _Float16* C16 = (_Float16*)Cp;
#pragma unroll
    for (int mt = 0; mt < 4; mt++)
#pragma unroll
        for (int r = 0; r < 4; r++) {
            int m = m0 + wm * 64 + mt * 16 + quad * 4 + r;
            if (m < M) {
#pragma unroll
                for (int nt = 0; nt < 4; nt++) {
                    int col = n0 + wn * 64 + nt * 16 + ln;
                    float v = acc[mt][nt][r];
                    if constexpr (HAS_BIAS) v += bv[nt];
                    if constexpr (SCALEQ) { if (col < DIM) v *= 0.18033688f; } // 0.125*log2(e)
                    if constexpr (OUT_HALF) C16[(size_t)m * N + col] = (_Float16)v;
                    else                    C32[(size_t)m * N + col] = v;
                }
            }
        }
}

// ---------------------------------------------------------------------------
// Flash attention v5 (unchanged from Round 3; 100us, conflicts 0).
// Block = 4 waves x 32 q = 128 q. O^T formulation:
//   S^T = K·Q^T (mfma 16x16x32, Q in registers as B-operand)
//   P^T (C-layout) is directly the B-frag of O^T += V^T·P^T (mfma 16x16x16).
// NO online softmax (Q pre-scaled by scale*log2e in QKV GEMM epilogue).
// Double-buffered global_load_lds staging, one barrier per tile.
// Layouts (proven: SQ_LDS_BANK_CONFLICT == 0):
//  * K tile [64][64], 16B chunks XOR-swizzled pos = dc ^ (key&7).
//  * V tile [4][16]-subtiled for ds_read_b64_tr_b16 (HW transpose read).
// ---------------------------------------------------------------------------
__global__ __launch_bounds__(256) void attn_f16(
    const _Float16* __restrict__ qkv, _Float16* __restrict__ outp)
{
    __shared__ _Float16 Ks[2][64 * 64];
    __shared__ _Float16 Vs[2][64 * 64];

    const int t    = threadIdx.x, lane = t & 63, wv = t >> 6;
    const int quad = lane >> 4,   ln   = lane & 15;
    const int q0   = blockIdx.x * 128;
    const int hd   = blockIdx.y,  b    = blockIdx.z;
    const _Float16* base = qkv + (size_t)b * SEQ * QKVN;

    // ---- Q fragments in registers (B-operand: n=q=ln, k=d=quad*8+j) ----
    half8 qreg[2][2];
#pragma unroll
    for (int qc = 0; qc < 2; qc++) {
        int q = q0 + wv * 32 + qc * 16 + ln; if (q >= SEQ) q = SEQ - 1;
#pragma unroll
        for (int kd = 0; kd < 2; kd++)
            qreg[qc][kd] = *(const half8*)(base + (size_t)q * QKVN + hd * HDIM + kd * 32 + quad * 8);
    }

    // ---- per-thread staging constants (swizzle folded into global addr) ----
    const int krow = t >> 3;                               // + {0,32}
    const int kdc  = (t & 7) ^ (krow & 7);
    const int vkey = ((t >> 7) << 4) + (((t >> 3) & 3) << 2) + ((t >> 1) & 3);  // + {0,32}
    const int vd0  = (((t >> 5) & 3) << 4) + ((t & 1) << 3);
    const _Float16* kcst = base + DIM     + hd * HDIM + kdc * 8;
    const _Float16* vcst = base + 2 * DIM + hd * HDIM + vd0;

    float lr[2] = {0.f, 0.f};
    floatx4 o[2][4];
#pragma unroll
    for (int qc = 0; qc < 2; qc++)
#pragma unroll
        for (int dt = 0; dt < 4; dt++) o[qc][dt] = {0.f, 0.f, 0.f, 0.f};

    const unsigned vb0 = lds_addr(&Vs[0][0]) + lane * 8;   // per-lane tr-read base

    // ---- prologue: stage tile 0 into buffer 0 (k0=0: no clamping needed) ----
    gld_lds16(kcst + (size_t)krow * QKVN,        &Ks[0][t * 8]);
    gld_lds16(kcst + (size_t)(krow + 32) * QKVN, &Ks[0][(t + 256) * 8]);
    gld_lds16(vcst + (size_t)vkey * QKVN,        &Vs[0][t * 8]);
    gld_lds16(vcst + (size_t)(vkey + 32) * QKVN, &Vs[0][(t + 256) * 8]);

    for (int kt0 = 0; kt0 < 10; kt0++) {
        const int cur = kt0 & 1;
        const int k0  = kt0 * 64;

        // implicit vmcnt(0) here drains tile kt0's loads — issued one full
        // compute phase ago (prologue or previous iteration) => hidden.
        __syncthreads();

        // ---- stage tile kt0+1 into the other buffer ----
        if (kt0 < 9) {
            const int k1 = k0 + 64, nb = cur ^ 1;
            int r0 = k1 + krow;      if (r0 > SEQ - 1) r0 = SEQ - 1;
            int r1 = k1 + krow + 32; if (r1 > SEQ - 1) r1 = SEQ - 1;
            int s0 = k1 + vkey;      if (s0 > SEQ - 1) s0 = SEQ - 1;
            int s1 = k1 + vkey + 32; if (s1 > SEQ - 1) s1 = SEQ - 1;
            gld_lds16(kcst + (size_t)r0 * QKVN, &Ks[nb][t * 8]);
            gld_lds16(kcst + (size_t)r1 * QKVN, &Ks[nb][(t + 256) * 8]);
            gld_lds16(vcst + (size_t)s0 * QKVN, &Vs[nb][t * 8]);
            gld_lds16(vcst + (size_t)s1 * QKVN, &Vs[nb][(t + 256) * 8]);
        }
        __builtin_amdgcn_sched_barrier(0);     // pin load issue before compute

        // ---- S^T = K·Q^T : 8 mfma 16x16x32 for 2 q-cols ----
        floatx4 sacc[2][4];
#pragma unroll
        for (int qc = 0; qc < 2; qc++)
#pragma unroll
            for (int mt = 0; mt < 4; mt++) sacc[qc][mt] = {0.f, 0.f, 0.f, 0.f};
        const int xr = ln & 7;
#pragma unroll
        for (int kd = 0; kd < 2; kd++) {
            half8 kf[4];
#pragma unroll
            for (int mt = 0; mt < 4; mt++)
                kf[mt] = *(const half8*)&Ks[cur][(mt * 16 + ln) * 64 + (((kd * 4 + quad) ^ xr) << 3)];
#pragma unroll
            for (int mt = 0; mt < 4; mt++) {
                sacc[0][mt] = __builtin_amdgcn_mfma_f32_16x16x32_f16(kf[mt], qreg[0][kd], sacc[0][mt], 0, 0, 0);
                sacc[1][mt] = __builtin_amdgcn_mfma_f32_16x16x32_f16(kf[mt], qreg[1][kd], sacc[1][mt], 0, 0, 0);
            }
        }

        // ---- issue ALL 16 V^T tr-reads; latency hides under mask+exp2 ----
        half4 vf[4][4];
        const unsigned vb = vb0 + (cur << 13);
#pragma unroll
        for (int kt = 0; kt < 4; kt++) {
            unsigned a = vb + kt * 2048;
            asm volatile("ds_read_b64_tr_b16 %0, %1 offset:0"    : "=v"(vf[kt][0]) : "v"(a));
            asm volatile("ds_read_b64_tr_b16 %0, %1 offset:512"  : "=v"(vf[kt][1]) : "v"(a));
            asm volatile("ds_read_b64_tr_b16 %0, %1 offset:1024" : "=v"(vf[kt][2]) : "v"(a));
            asm volatile("ds_read_b64_tr_b16 %0, %1 offset:1536" : "=v"(vf[kt][3]) : "v"(a));
        }

        // ---- mask padding keys (only last tile; wave-uniform branch) ----
        if (k0 + 64 > SEQ) {
#pragma unroll
            for (int mt = 0; mt < 4; mt++)
#pragma unroll
                for (int r = 0; r < 4; r++)
                    if (k0 + mt * 16 + quad * 4 + r >= SEQ) {
                        sacc[0][mt][r] = -3e38f;
                        sacc[1][mt][r] = -3e38f;
                    }
        }

        // ---- softmax numerator (scores already in log2 units) ----
        half4 pf[2][4];
#pragma unroll
        for (int qc = 0; qc < 2; qc++) {
#pragma unroll
            for (int mt = 0; mt < 4; mt++)
#pragma unroll
                for (int r = 0; r < 4; r++) {
                    float p = exp2f(sacc[qc][mt][r]);
                    lr[qc] += p;                  // per-lane partial; reduced after k-loop
                    pf[qc][mt][r] = (_Float16)p;
                }
        }

        // ---- single drain, then 32 back-to-back PV MFMAs ----
        asm volatile("s_waitcnt lgkmcnt(0)" ::: "memory");
        __builtin_amdgcn_sched_barrier(0);   // rule #18: fence MFMA hoist
#pragma unroll
        for (int kt = 0; kt < 4; kt++) {
#pragma unroll
            for (int dt = 0; dt < 4; dt++) {
                o[0][dt] = __builtin_amdgcn_mfma_f32_16x16x16f16(vf[kt][dt], pf[0][kt], o[0][dt], 0, 0, 0);
                o[1][dt] = __builtin_amdgcn_mfma_f32_16x16x16f16(vf[kt][dt], pf[1][kt], o[1][dt], 0, 0, 0);
            }
        }
    }

    // ---- denominator reduction (once, after k-loop) ----
#pragma unroll
    for (int qc = 0; qc < 2; qc++) {
        lr[qc] += __shfl_xor(lr[qc], 16);
        lr[qc] += __shfl_xor(lr[qc], 32);
    }

    // ---- normalize + store (8B contiguous per dt) ----
#pragma unroll
    for (int qc = 0; qc < 2; qc++) {
        int q = q0 + wv * 32 + qc * 16 + ln;
        if (q < SEQ) {
            float inv = 1.f / lr[qc];
#pragma unroll
            for (int dt = 0; dt < 4; dt++) {
                half4 hv;
                hv[0] = (_Float16)(o[qc][dt][0] * inv);
                hv[1] = (_Float16)(o[qc][dt][1] * inv);
                hv[2] = (_Float16)(o[qc][dt][2] * inv);
                hv[3] = (_Float16)(o[qc][dt][3] * inv);
                *(half4*)&outp[(size_t)(b * SEQ + q) * DIM + hd * HDIM + dt * 16 + quad * 4] = hv;
            }
        }
    }
}

// ---------------------------------------------------------------------------
// cvt(all 3) -> qkv GEMM (Q pre-scaled) -> attention -> proj GEMM
// ---------------------------------------------------------------------------
extern "C" void kernel_launch(void* const* d_in, const int* in_sizes, int n_in,
                              void* d_out, int out_size, void* d_ws, size_t ws_size,
                              hipStream_t stream)
{
    const float* x     = (const float*)d_in[0];
    const float* Wqkv  = (const float*)d_in[1];
    const float* Wproj = (const float*)d_in[2];
    const float* bproj = (const float*)d_in[3];
    float* out = (float*)d_out;

    const size_t NX  = (size_t)MROWS * DIM;
    const size_t NWQ = (size_t)QKVN * DIM;
    const size_t NWP = (size_t)DIM * DIM;

    _Float16* x16    = (_Float16*)d_ws;
    _Float16* Wq16   = x16 + NX;
    _Float16* Wp16   = Wq16 + NWQ;
    _Float16* qkv16  = Wp16 + NWP;
    _Float16* attn16 = qkv16 + (size_t)MROWS * QKVN;

    cvt3_f32_f16<<<2048, 256, 0, stream>>>(x, x16, (int)(NX / 4),
                                           Wqkv, Wq16, (int)(NWQ / 4),
                                           Wproj, Wp16, (int)(NWP / 4));

    {
        int npm = (MROWS + 127) / 128, npn = QKVN / 128;
        gemm_f16_reg<1, 0, 1><<<npm * npn, 256, 0, stream>>>(
            x16, Wq16, nullptr, qkv16, MROWS, QKVN, DIM, npm, npn);
    }

    attn_f16<<<dim3((SEQ + 127) / 128, NHEAD, BATCH), 256, 0, stream>>>(qkv16, attn16);

    {
        int npm = (MROWS + 127) / 128, npn = DIM / 128;
        gemm_f16_reg<0, 1, 0><<<npm * npn, 256, 0, stream>>>(
            attn16, Wp16, bproj, out, MROWS, DIM, DIM, npm, npn);
    }
}

// Round 8
// 333.240 us; speedup vs baseline: 1.6435x; 1.6435x over previous
//
#include <hip/hip_runtime.h>
#include <math.h>

#define SEQ    577
#define BATCH  32
#define DIM    768
#define NHEAD  12
#define HDIM   64
#define MROWS  (BATCH * SEQ)      // 18464
#define QKVN   (3 * DIM)          // 2304

using half4   = __attribute__((ext_vector_type(4))) _Float16;
using half8   = __attribute__((ext_vector_type(8))) _Float16;
using floatx4 = __attribute__((ext_vector_type(4))) float;

typedef __attribute__((address_space(1))) const unsigned int GU;
typedef __attribute__((address_space(3))) unsigned int LU;

__device__ __forceinline__ void gld_lds16(const _Float16* g, _Float16* l) {
    __builtin_amdgcn_global_load_lds((const GU*)g, (LU*)l, 16, 0, 0);
}

__device__ __forceinline__ unsigned lds_addr(const void* p) {
    return (unsigned)(size_t)(LU*)p;   // addrspacecast generic -> LDS offset
}

// ---------------------------------------------------------------------------
// fp32 -> fp16 convert, 3 segments in one launch (x, Wqkv, Wproj).
// ---------------------------------------------------------------------------
__global__ void cvt3_f32_f16(const float* __restrict__ a, _Float16* __restrict__ ao, int na4,
                             const float* __restrict__ b, _Float16* __restrict__ bo, int nb4,
                             const float* __restrict__ c, _Float16* __restrict__ co, int nc4)
{
    int i = blockIdx.x * blockDim.x + threadIdx.x;
    int stride = gridDim.x * blockDim.x;
    int total = na4 + nb4 + nc4;
    for (; i < total; i += stride) {
        const float4* src; half4* dst; int j = i;
        if (j < na4)            { src = (const float4*)a; dst = (half4*)ao; }
        else if ((j -= na4) < nb4) { src = (const float4*)b; dst = (half4*)bo; }
        else { j -= nb4;          src = (const float4*)c; dst = (half4*)co; }
        float4 v = src[j];
        half4 h;
        h[0] = (_Float16)v.x; h[1] = (_Float16)v.y;
        h[2] = (_Float16)v.z; h[3] = (_Float16)v.w;
        dst[j] = h;
    }
}

// ---------------------------------------------------------------------------
// fp16 GEMM v6: C[M,N]=A[M,K]@B[N,K]^T (+bias). 256x256 block, 8 waves
// (512 thr), wave tile 128x64 (HK geometry), BK=64 as two 32-col panels,
// v_mfma_f32_16x16x32_f16, GROUP_M=8 L2 swizzle.
//
// Why: R4-R6 held at 105us / MfmaUtil 26% across three schedules; R7 no-LDS
// fell to 10% (VMEM segment-bound). Invariant cause: 64x64 wave tiles ->
// LDS-read bytes/FLOP ~ (wM+wN)/(wM*wN) = 1/32; LDS pipe ~2.5x matrix pipe.
// 128x64 wave tiles give 1/42.7 (1.33x less) AND 2x MFMA work per barrier
// interval -> LDS:MFMA drops to ~1.6:1.
// Carried-over proven pieces:
//  * 16B-chunk XOR bank swizzle folded into the GLOBAL source address (LDS
//    dest stays linear for global_load_lds); read at quad^((ln>>1)&3).
//    Conflicts measured 0 at identical read pattern (R4-R6).
//  * R5 counted-vmcnt 2-deep pipeline: 8 loads/thread/K-step, vmcnt(8)
//    drains only tile t, raw s_barrier (no implicit vmcnt(0)), stage t+2
//    after the read-complete barrier.
// LDS 128KB (1 block/CU, 8 waves, 2/SIMD). VGPR: acc 128 + frags 48 ->
// ~210; __launch_bounds__(512,2) caps at 256.
//
// SCALEQ: multiply cols < DIM by scale*log2(e) in the f32 epilogue so the
// attention kernel can exp2 the raw MFMA scores with no per-element mul.
// ---------------------------------------------------------------------------
template<int OUT_HALF, int HAS_BIAS, int SCALEQ>
__global__ __launch_bounds__(512, 2) void gemm_f16_256(
    const _Float16* __restrict__ A, const _Float16* __restrict__ B,
    const float* __restrict__ bias, void* __restrict__ Cp,
    int M, int N, int K, int npm, int npn)
{
    __shared__ _Float16 As[2][2 * 256 * 32];   // [dbuf][panel|row|chunk] 32KB/buf
    __shared__ _Float16 Bs[2][2 * 256 * 32];

    const int GROUP = 8;
    int pid  = blockIdx.x;
    int ngrp = GROUP * npn;
    int g    = pid / ngrp;
    int fm   = g * GROUP;
    int gm   = npm - fm; if (gm > GROUP) gm = GROUP;
    int pm   = fm + (pid % ngrp) % gm;
    int pn   = (pid % ngrp) / gm;
    const int m0 = pm * 256, n0 = pn * 256;

    const int t    = threadIdx.x, lane = t & 63, wv = t >> 6;
    const int quad = lane >> 4,   ln   = lane & 15;
    const int wr   = wv >> 2,     wc   = wv & 3;   // 2x4 wave grid

    floatx4 acc[8][4];
#pragma unroll
    for (int mt = 0; mt < 8; mt++)
#pragma unroll
        for (int nt = 0; nt < 4; nt++) acc[mt][nt] = {0.f, 0.f, 0.f, 0.f};

    // ---- staging decode: thread t stages chunks {t, t+512, t+1024, t+1536}
    // of each tile. Chunk CH: panel=CH>>10, row=(CH&1023)>>2, cc=CH&3.
    // LDS dest linear at CH*16B; global source col-chunk = cc^((row>>1)&3).
    const _Float16* Ag[4];
    const _Float16* Bg[4];
    int ldst[4];
#pragma unroll
    for (int i = 0; i < 4; i++) {
        const int CH    = t + (i << 9);
        const int panel = CH >> 10;
        const int rem   = CH & 1023;
        const int row   = rem >> 2;
        const int cc    = rem & 3;
        const int scc   = cc ^ ((row >> 1) & 3);         // bank swizzle (R4-proven)
        int ma = m0 + row; if (ma > M - 1) ma = M - 1;   // M-tail clamp
        Ag[i]   = A + (size_t)ma * K + panel * 32 + scc * 8;
        Bg[i]   = B + (size_t)(n0 + row) * K + panel * 32 + scc * 8;  // N%256==0
        ldst[i] = CH * 8;
    }

    const int nk = K >> 6;                  // 12 K-steps of 64

#define STAGE_G(it, buf)                                            \
    {                                                               \
        const int ko_ = (it) << 6;                                  \
        _Pragma("unroll")                                           \
        for (int i2 = 0; i2 < 4; i2++) {                            \
            gld_lds16(Ag[i2] + ko_, &As[(buf)][ldst[i2]]);          \
            gld_lds16(Bg[i2] + ko_, &Bs[(buf)][ldst[i2]]);          \
        }                                                           \
    }

    // ---- prologue: 2-deep prefetch (16 loads/thread in flight) ----
    STAGE_G(0, 0);
    STAGE_G(1, 1);

    const int rq = (ln >> 1) & 3;           // read-side swizzle key

    for (int it = 0; it < nk; it++) {
        const int cur = it & 1;

        // drain ONLY tile it's 8 loads; tile it+1's stay in flight.
        if (it + 1 < nk) asm volatile("s_waitcnt vmcnt(8)" ::: "memory");
        else             asm volatile("s_waitcnt vmcnt(0)" ::: "memory");
        __builtin_amdgcn_s_barrier();          // raw: no implicit vmcnt(0)
        __builtin_amdgcn_sched_barrier(0);

#pragma unroll
        for (int p = 0; p < 2; p++) {
            half8 af[8], bf[4];
#pragma unroll
            for (int mt = 0; mt < 8; mt++)
                af[mt] = *(const half8*)&As[cur][p * 8192 + (wr * 128 + mt * 16 + ln) * 32 + ((quad ^ rq) << 3)];
#pragma unroll
            for (int nt = 0; nt < 4; nt++)
                bf[nt] = *(const half8*)&Bs[cur][p * 8192 + (wc * 64 + nt * 16 + ln) * 32 + ((quad ^ rq) << 3)];
#pragma unroll
            for (int mt = 0; mt < 8; mt++)
#pragma unroll
                for (int nt = 0; nt < 4; nt++)
                    acc[mt][nt] = __builtin_amdgcn_mfma_f32_16x16x32_f16(
                        af[mt], bf[nt], acc[mt][nt], 0, 0, 0);
        }

        __builtin_amdgcn_sched_barrier(0);
        __builtin_amdgcn_s_barrier();          // all waves done reading buf[cur]
        if (it + 2 < nk) STAGE_G(it + 2, cur); // overwrite the freed buffer
    }
#undef STAGE_G

    float bv[4];
    if constexpr (HAS_BIAS) {
#pragma unroll
        for (int nt = 0; nt < 4; nt++) bv[nt] = bias[n0 + wc * 64 + nt * 16 + ln];
    }
    float*    C32 = (float*)Cp;
    _Float16* C16 = (_Float16*)Cp;
#pragma unroll
    for (int mt = 0; mt < 8; mt++)
#pragma unroll
        for (int r = 0; r < 4; r++) {
            int m = m0 + wr * 128 + mt * 16 + quad * 4 + r;
            if (m < M) {
#pragma unroll
                for (int nt = 0; nt < 4; nt++) {
                    int col = n0 + wc * 64 + nt * 16 + ln;
                    float v = acc[mt][nt][r];
                    if constexpr (HAS_BIAS) v += bv[nt];
                    if constexpr (SCALEQ) { if (col < DIM) v *= 0.18033688f; } // 0.125*log2(e)
                    if constexpr (OUT_HALF) C16[(size_t)m * N + col] = (_Float16)v;
                    else                    C32[(size_t)m * N + col] = v;
                }
            }
        }
}

// ---------------------------------------------------------------------------
// Flash attention v5 (unchanged from Round 3; 100us, conflicts 0).
// Block = 4 waves x 32 q = 128 q. O^T formulation:
//   S^T = K·Q^T (mfma 16x16x32, Q in registers as B-operand)
//   P^T (C-layout) is directly the B-frag of O^T += V^T·P^T (mfma 16x16x16).
// NO online softmax (Q pre-scaled by scale*log2e in QKV GEMM epilogue).
// Double-buffered global_load_lds staging, one barrier per tile.
// Layouts (proven: SQ_LDS_BANK_CONFLICT == 0):
//  * K tile [64][64], 16B chunks XOR-swizzled pos = dc ^ (key&7).
//  * V tile [4][16]-subtiled for ds_read_b64_tr_b16 (HW transpose read).
// ---------------------------------------------------------------------------
__global__ __launch_bounds__(256) void attn_f16(
    const _Float16* __restrict__ qkv, _Float16* __restrict__ outp)
{
    __shared__ _Float16 Ks[2][64 * 64];
    __shared__ _Float16 Vs[2][64 * 64];

    const int t    = threadIdx.x, lane = t & 63, wv = t >> 6;
    const int quad = lane >> 4,   ln   = lane & 15;
    const int q0   = blockIdx.x * 128;
    const int hd   = blockIdx.y,  b    = blockIdx.z;
    const _Float16* base = qkv + (size_t)b * SEQ * QKVN;

    // ---- Q fragments in registers (B-operand: n=q=ln, k=d=quad*8+j) ----
    half8 qreg[2][2];
#pragma unroll
    for (int qc = 0; qc < 2; qc++) {
        int q = q0 + wv * 32 + qc * 16 + ln; if (q >= SEQ) q = SEQ - 1;
#pragma unroll
        for (int kd = 0; kd < 2; kd++)
            qreg[qc][kd] = *(const half8*)(base + (size_t)q * QKVN + hd * HDIM + kd * 32 + quad * 8);
    }

    // ---- per-thread staging constants (swizzle folded into global addr) ----
    const int krow = t >> 3;                               // + {0,32}
    const int kdc  = (t & 7) ^ (krow & 7);
    const int vkey = ((t >> 7) << 4) + (((t >> 3) & 3) << 2) + ((t >> 1) & 3);  // + {0,32}
    const int vd0  = (((t >> 5) & 3) << 4) + ((t & 1) << 3);
    const _Float16* kcst = base + DIM     + hd * HDIM + kdc * 8;
    const _Float16* vcst = base + 2 * DIM + hd * HDIM + vd0;

    float lr[2] = {0.f, 0.f};
    floatx4 o[2][4];
#pragma unroll
    for (int qc = 0; qc < 2; qc++)
#pragma unroll
        for (int dt = 0; dt < 4; dt++) o[qc][dt] = {0.f, 0.f, 0.f, 0.f};

    const unsigned vb0 = lds_addr(&Vs[0][0]) + lane * 8;   // per-lane tr-read base

    // ---- prologue: stage tile 0 into buffer 0 (k0=0: no clamping needed) ----
    gld_lds16(kcst + (size_t)krow * QKVN,        &Ks[0][t * 8]);
    gld_lds16(kcst + (size_t)(krow + 32) * QKVN, &Ks[0][(t + 256) * 8]);
    gld_lds16(vcst + (size_t)vkey * QKVN,        &Vs[0][t * 8]);
    gld_lds16(vcst + (size_t)(vkey + 32) * QKVN, &Vs[0][(t + 256) * 8]);

    for (int kt0 = 0; kt0 < 10; kt0++) {
        const int cur = kt0 & 1;
        const int k0  = kt0 * 64;

        // implicit vmcnt(0) here drains tile kt0's loads — issued one full
        // compute phase ago (prologue or previous iteration) => hidden.
        __syncthreads();

        // ---- stage tile kt0+1 into the other buffer ----
        if (kt0 < 9) {
            const int k1 = k0 + 64, nb = cur ^ 1;
            int r0 = k1 + krow;      if (r0 > SEQ - 1) r0 = SEQ - 1;
            int r1 = k1 + krow + 32; if (r1 > SEQ - 1) r1 = SEQ - 1;
            int s0 = k1 + vkey;      if (s0 > SEQ - 1) s0 = SEQ - 1;
            int s1 = k1 + vkey + 32; if (s1 > SEQ - 1) s1 = SEQ - 1;
            gld_lds16(kcst + (size_t)r0 * QKVN, &Ks[nb][t * 8]);
            gld_lds16(kcst + (size_t)r1 * QKVN, &Ks[nb][(t + 256) * 8]);
            gld_lds16(vcst + (size_t)s0 * QKVN, &Vs[nb][t * 8]);
            gld_lds16(vcst + (size_t)s1 * QKVN, &Vs[nb][(t + 256) * 8]);
        }
        __builtin_amdgcn_sched_barrier(0);     // pin load issue before compute

        // ---- S^T = K·Q^T : 8 mfma 16x16x32 for 2 q-cols ----
        floatx4 sacc[2][4];
#pragma unroll
        for (int qc = 0; qc < 2; qc++)
#pragma unroll
            for (int mt = 0; mt < 4; mt++) sacc[qc][mt] = {0.f, 0.f, 0.f, 0.f};
        const int xr = ln & 7;
#pragma unroll
        for (int kd = 0; kd < 2; kd++) {
            half8 kf[4];
#pragma unroll
            for (int mt = 0; mt < 4; mt++)
                kf[mt] = *(const half8*)&Ks[cur][(mt * 16 + ln) * 64 + (((kd * 4 + quad) ^ xr) << 3)];
#pragma unroll
            for (int mt = 0; mt < 4; mt++) {
                sacc[0][mt] = __builtin_amdgcn_mfma_f32_16x16x32_f16(kf[mt], qreg[0][kd], sacc[0][mt], 0, 0, 0);
                sacc[1][mt] = __builtin_amdgcn_mfma_f32_16x16x32_f16(kf[mt], qreg[1][kd], sacc[1][mt], 0, 0, 0);
            }
        }

        // ---- issue ALL 16 V^T tr-reads; latency hides under mask+exp2 ----
        half4 vf[4][4];
        const unsigned vb = vb0 + (cur << 13);
#pragma unroll
        for (int kt = 0; kt < 4; kt++) {
            unsigned a = vb + kt * 2048;
            asm volatile("ds_read_b64_tr_b16 %0, %1 offset:0"    : "=v"(vf[kt][0]) : "v"(a));
            asm volatile("ds_read_b64_tr_b16 %0, %1 offset:512"  : "=v"(vf[kt][1]) : "v"(a));
            asm volatile("ds_read_b64_tr_b16 %0, %1 offset:1024" : "=v"(vf[kt][2]) : "v"(a));
            asm volatile("ds_read_b64_tr_b16 %0, %1 offset:1536" : "=v"(vf[kt][3]) : "v"(a));
        }

        // ---- mask padding keys (only last tile; wave-uniform branch) ----
        if (k0 + 64 > SEQ) {
#pragma unroll
            for (int mt = 0; mt < 4; mt++)
#pragma unroll
                for (int r = 0; r < 4; r++)
                    if (k0 + mt * 16 + quad * 4 + r >= SEQ) {
                        sacc[0][mt][r] = -3e38f;
                        sacc[1][mt][r] = -3e38f;
                    }
        }

        // ---- softmax numerator (scores already in log2 units) ----
        half4 pf[2][4];
#pragma unroll
        for (int qc = 0; qc < 2; qc++) {
#pragma unroll
            for (int mt = 0; mt < 4; mt++)
#pragma unroll
                for (int r = 0; r < 4; r++) {
                    float p = exp2f(sacc[qc][mt][r]);
                    lr[qc] += p;                  // per-lane partial; reduced after k-loop
                    pf[qc][mt][r] = (_Float16)p;
                }
        }

        // ---- single drain, then 32 back-to-back PV MFMAs ----
        asm volatile("s_waitcnt lgkmcnt(0)" ::: "memory");
        __builtin_amdgcn_sched_barrier(0);   // rule #18: fence MFMA hoist
#pragma unroll
        for (int kt = 0; kt < 4; kt++) {
#pragma unroll
            for (int dt = 0; dt < 4; dt++) {
                o[0][dt] = __builtin_amdgcn_mfma_f32_16x16x16f16(vf[kt][dt], pf[0][kt], o[0][dt], 0, 0, 0);
                o[1][dt] = __builtin_amdgcn_mfma_f32_16x16x16f16(vf[kt][dt], pf[1][kt], o[1][dt], 0, 0, 0);
            }
        }
    }

    // ---- denominator reduction (once, after k-loop) ----
#pragma unroll
    for (int qc = 0; qc < 2; qc++) {
        lr[qc] += __shfl_xor(lr[qc], 16);
        lr[qc] += __shfl_xor(lr[qc], 32);
    }

    // ---- normalize + store (8B contiguous per dt) ----
#pragma unroll
    for (int qc = 0; qc < 2; qc++) {
        int q = q0 + wv * 32 + qc * 16 + ln;
        if (q < SEQ) {
            float inv = 1.f / lr[qc];
#pragma unroll
            for (int dt = 0; dt < 4; dt++) {
                half4 hv;
                hv[0] = (_Float16)(o[qc][dt][0] * inv);
                hv[1] = (_Float16)(o[qc][dt][1] * inv);
                hv[2] = (_Float16)(o[qc][dt][2] * inv);
                hv[3] = (_Float16)(o[qc][dt][3] * inv);
                *(half4*)&outp[(size_t)(b * SEQ + q) * DIM + hd * HDIM + dt * 16 + quad * 4] = hv;
            }
        }
    }
}

// ---------------------------------------------------------------------------
// cvt(all 3) -> qkv GEMM (Q pre-scaled) -> attention -> proj GEMM
// ---------------------------------------------------------------------------
extern "C" void kernel_launch(void* const* d_in, const int* in_sizes, int n_in,
                              void* d_out, int out_size, void* d_ws, size_t ws_size,
                              hipStream_t stream)
{
    const float* x     = (const float*)d_in[0];
    const float* Wqkv  = (const float*)d_in[1];
    const float* Wproj = (const float*)d_in[2];
    const float* bproj = (const float*)d_in[3];
    float* out = (float*)d_out;

    const size_t NX  = (size_t)MROWS * DIM;
    const size_t NWQ = (size_t)QKVN * DIM;
    const size_t NWP = (size_t)DIM * DIM;

    _Float16* x16    = (_Float16*)d_ws;
    _Float16* Wq16   = x16 + NX;
    _Float16* Wp16   = Wq16 + NWQ;
    _Float16* qkv16  = Wp16 + NWP;
    _Float16* attn16 = qkv16 + (size_t)MROWS * QKVN;

    cvt3_f32_f16<<<2048, 256, 0, stream>>>(x, x16, (int)(NX / 4),
                                           Wqkv, Wq16, (int)(NWQ / 4),
                                           Wproj, Wp16, (int)(NWP / 4));

    {
        int npm = (MROWS + 255) / 256, npn = QKVN / 256;
        gemm_f16_256<1, 0, 1><<<npm * npn, 512, 0, stream>>>(
            x16, Wq16, nullptr, qkv16, MROWS, QKVN, DIM, npm, npn);
    }

    attn_f16<<<dim3((SEQ + 127) / 128, NHEAD, BATCH), 256, 0, stream>>>(qkv16, attn16);

    {
        int npm = (MROWS + 255) / 256, npn = DIM / 256;
        gemm_f16_256<0, 1, 0><<<npm * npn, 512, 0, stream>>>(
            attn16, Wp16, bproj, out, MROWS, DIM, DIM, npm, npn);
    }
}